// Round 13
// baseline (265.216 us; speedup 1.0000x reference)
//
#include <hip/hip_runtime.h>
#include <hip/hip_bf16.h>

typedef __attribute__((ext_vector_type(8))) __bf16 bf16x8;
typedef __attribute__((ext_vector_type(4))) __bf16 bf16x4;
typedef __attribute__((ext_vector_type(4))) float f32x4;

#define DIN 1024
#define DOUT 1024
#define MROWS 16384
#define POOLN 5
#define RR 8
#define NTASKS 5
#define TOPKK 3

// Device-scope grid barrier. SAFE ONLY because the grid is provably fully
// co-resident: 512 blocks x 512 thr, 72KB LDS, launch_bounds(512,4) ->
// exactly 2 blocks/CU x 256 CU = 512. Fresh counter per phase (no reuse).
__device__ __forceinline__ void grid_barrier(unsigned* cnt) {
    __syncthreads();
    if (threadIdx.x == 0) {
        __threadfence();                       // release: my writes visible
        atomicAdd(cnt, 1u);
        while (__hip_atomic_load(cnt, __ATOMIC_RELAXED, __HIP_MEMORY_SCOPE_AGENT) < 512u)
            __builtin_amdgcn_s_sleep(2);
        __threadfence();                       // acquire: drop stale caches
    }
    __syncthreads();
}

__global__ __launch_bounds__(512, 4) void kFused(
        const float* __restrict__ in, const float* __restrict__ W,
        const float* __restrict__ ldown, const float* __restrict__ lup,
        const float* __restrict__ lroute, const int* __restrict__ task_id_p,
        __bf16* __restrict__ Wb0, __bf16* __restrict__ Wb1,
        float* __restrict__ partial, float* __restrict__ partial2,
        float* __restrict__ gate, int* __restrict__ gidx,
        unsigned* __restrict__ cnt, float* __restrict__ C) {
    __shared__ ushort ldsU[36864];             // 72 KB, reused across phases
    const int b = blockIdx.x;                  // 0..511
    const int t = threadIdx.x;                 // 0..511

    // ================= Phase A: colsum partials (64 MB read) =================
    {
        const f32x4* __restrict__ inv = (const f32x4*)in;
        const int tid0 = b * 512 + t;          // 0..262143
        float s0 = 0.f, s1 = 0.f, s2 = 0.f, s3 = 0.f;
        size_t idx = tid0;                     // stride 262144 f4 == 0 mod 256
        f32x4 cur = inv[idx];
#pragma unroll
        for (int i = 0; i < 16; ++i) {
            f32x4 nxt = cur;
            if (i < 15) nxt = inv[idx + 262144];
            s0 += cur[0]; s1 += cur[1]; s2 += cur[2]; s3 += cur[3];
            cur = nxt; idx += 262144;
        }
        const int pr = b * 2 + (t >> 8);       // 0..1023
        const int c0 = (t * 4) & (DIN - 1);
        f32x4 p = { s0, s1, s2, s3 };
        *(f32x4*)&partial[(size_t)pr * DIN + c0] = p;
    }
    grid_barrier(&cnt[0]);

    // ================= Phase B: reduce 1024 partial rows -> partial2[8][1024]
    if (b < 16) {
        const int tid = b * 512 + t;           // 0..8191
        const int c = tid & (DIN - 1);
        const int g = tid >> 10;               // 0..7
        float s = 0.f;
        const int r0 = g * 128;
#pragma unroll 8
        for (int r = r0; r < r0 + 128; ++r) s += partial[(size_t)r * DIN + c];
        partial2[(size_t)g * DIN + c] = s;
    }
    grid_barrier(&cnt[1]);

    // ================= Phase C: omegas -> top-k -> softmax gate (block 0) ====
    if (b == 0) {
        float (*red)[POOLN] = (float(*)[POOLN])ldsU;
        if (t < 256) {
            const int w = t >> 6, l = t & 63;
            float part[POOLN] = {0.f, 0.f, 0.f, 0.f, 0.f};
            for (int d = w * 256 + l; d < w * 256 + 256; d += 64) {
                float cs = 0.f;
#pragma unroll
                for (int g = 0; g < 8; ++g) cs += partial2[g * DIN + d];
                cs *= (1.0f / (float)MROWS);
                const float* rp = &lroute[(size_t)1 * DIN * POOLN + (size_t)d * POOLN];
#pragma unroll
                for (int p = 0; p < POOLN; ++p) part[p] += cs * rp[p];
            }
#pragma unroll
            for (int p = 0; p < POOLN; ++p) {
                float v = part[p];
                for (int off = 32; off; off >>= 1) v += __shfl_down(v, off);
                if (l == 0) red[w][p] = v;
            }
        }
        __syncthreads();
        if (t == 0) {
            float part[POOLN];
#pragma unroll
            for (int p = 0; p < POOLN; ++p)
                part[p] = red[0][p] + red[1][p] + red[2][p] + red[3][p];
            int tid = *task_id_p;
            if (tid > NTASKS) tid = NTASKS;
            int L = tid < (POOLN - 1) ? tid : (POOLN - 1);
            int k = tid < TOPKK ? tid : TOPKK;
            float sl[POOLN];
            for (int j = 0; j < L; ++j) sl[j] = part[1 + j];
            float G[TOPKK]; int I[TOPKK];
            int used = 0;
            for (int j = 0; j < k; ++j) {
                int best = -1; float bv = 0.f;
                for (int i2 = 0; i2 < L; ++i2) {
                    if (used & (1 << i2)) continue;
                    if (best < 0 || sl[i2] > bv) { bv = sl[i2]; best = i2; }
                }
                used |= 1 << best; G[j] = bv; I[j] = best;
            }
            float gt[TOPKK] = {0.f, 0.f, 0.f};
            int   gi[TOPKK] = {0, 0, 0};
            if (k > 0) {
                float m = G[0];
                float e[TOPKK]; float se = 0.f;
                for (int j = 0; j < k; ++j) { e[j] = expf(G[j] - m); se += e[j]; }
                for (int j = 0; j < k; ++j) { gt[j] = e[j] / se; gi[j] = I[j]; }
            }
#pragma unroll
            for (int j = 0; j < TOPKK; ++j) { gate[j] = gt[j]; gidx[j] = gi[j]; }
        }
    }
    grid_barrier(&cnt[2]);

    // ================= Phase D: build Wb0/Wb1 (o = 2b + (t>>8)) ==============
    {
        const int o = 2 * b + (t >> 8);
        const int tl = t & 255;
        float c[TOPKK][RR];
#pragma unroll
        for (int j = 0; j < TOPKK; ++j) {
            const float g = gate[j];
            const int   p = gidx[j];
#pragma unroll
            for (int r = 0; r < RR; ++r)
                c[j][r] = g * lup[(size_t)p * RR * DOUT + (size_t)r * DOUT + o];
        }
        const int d0 = tl * 4;
        const float4 wv = *(const float4*)&W[(size_t)o * DIN + d0];
        float outv[4] = { wv.x, wv.y, wv.z, wv.w };
        float dwv[4]  = { 0.f, 0.f, 0.f, 0.f };
#pragma unroll
        for (int j = 0; j < TOPKK; ++j) {
            const int p = gidx[j];
#pragma unroll
            for (int dd = 0; dd < 4; ++dd) {
                const float4 da = *(const float4*)&ldown[(size_t)p * DIN * RR + (size_t)(d0 + dd) * RR];
                const float4 db = *(const float4*)&ldown[(size_t)p * DIN * RR + (size_t)(d0 + dd) * RR + 4];
                dwv[dd] += da.x * c[j][0] + da.y * c[j][1] + da.z * c[j][2] + da.w * c[j][3]
                         + db.x * c[j][4] + db.y * c[j][5] + db.z * c[j][6] + db.w * c[j][7];
            }
        }
        bf16x4 b0 = { (__bf16)outv[0], (__bf16)outv[1], (__bf16)outv[2], (__bf16)outv[3] };
        bf16x4 b1 = { (__bf16)(outv[0] + dwv[0]), (__bf16)(outv[1] + dwv[1]),
                      (__bf16)(outv[2] + dwv[2]), (__bf16)(outv[3] + dwv[3]) };
        *(bf16x4*)&Wb0[(size_t)o * DIN + d0] = b0;
        *(bf16x4*)&Wb1[(size_t)o * DIN + d0] = b1;
    }
    grid_barrier(&cnt[3]);

    // ================= Phase E: 128x256 GEMM (R12 k4 body, verbatim) =========
    {
        ushort* lds = ldsU;
        const int bid = b;
        const int xcd = bid & 7;
        const int idx = bid >> 3;
        const int tm  = xcd * 16 + (idx >> 2);
        const int tn  = idx & 3;
        const __bf16* __restrict__ Bt = (tm >= 64) ? Wb1 : Wb0;

        const int tix  = t;
        const int lane = tix & 63;
        const int wid  = tix >> 6;
        const int wm = wid >> 2, wn = wid & 3;

        const int ar = tix >> 2;
        const int ac = tix & 3;
        const f32x4* __restrict__ pA = (const f32x4*)(in + ((size_t)(tm * 128 + ar)) * 1024 + ac * 8);
        const int awrp  = tix >> 3;
        const int awslot= ((tix & 3) + 4 * ((tix >> 2) & 1)) ^ (awrp & 7);
        const int awoff = awrp * 64 + awslot * 8;

        const int rpl  = lane >> 3;
        const int sl   = (lane & 7) ^ rpl;
        const int srow = rpl * 2 + (sl >> 2);
        const int sc   = sl & 3;
        const char* gB = (const char*)Bt + ((size_t)(tn*256 + wid*32 + srow)) * 2048 + sc * 16;
        const int ldsBst = 4096 + wid * 1024;

        const int rhalf = (lane & 15) >> 1;
        const int slot  = ((lane >> 4) + 4 * (lane & 1)) ^ rhalf;
        const int aoff  = (wm * 32 + rhalf) * 64 + slot * 8;
        const int boff  = 4096 + (wn * 32 + rhalf) * 64 + slot * 8;

        f32x4 acc[4][4];
#pragma unroll
        for (int i = 0; i < 4; ++i)
#pragma unroll
            for (int j = 0; j < 4; ++j) acc[i][j] = (f32x4){0.f, 0.f, 0.f, 0.f};

        auto issueB = [&](int s) {
            const int p = s % 3;
            const size_t kb = (size_t)s * 64;
#pragma unroll
            for (int j = 0; j < 2; ++j) {
                __builtin_amdgcn_global_load_lds(
                    (const __attribute__((address_space(1))) void*)(gB + (size_t)j * 32768 + kb),
                    (__attribute__((address_space(3))) void*)&lds[p * 12288 + ldsBst + j * 512],
                    16, 0, 0);
            }
        };
        auto writeA = [&](int s, f32x4 a0, f32x4 a1) {
            const int p = s % 3;
            bf16x8 v = { (__bf16)a0[0], (__bf16)a0[1], (__bf16)a0[2], (__bf16)a0[3],
                         (__bf16)a1[0], (__bf16)a1[1], (__bf16)a1[2], (__bf16)a1[3] };
            *(bf16x8*)&lds[p * 12288 + awoff] = v;
        };
        auto computeSlab = [&](int s) {
            const int p = s % 3;
            const ushort* aB = &lds[p * 12288 + aoff];
            const ushort* bB = &lds[p * 12288 + boff];
            bf16x8 a[4], bb[4];
#pragma unroll
            for (int mi = 0; mi < 4; ++mi) a[mi] = *(const bf16x8*)(aB + mi * 512);
#pragma unroll
            for (int ni = 0; ni < 4; ++ni) bb[ni] = *(const bf16x8*)(bB + ni * 512);
            __builtin_amdgcn_s_setprio(1);
#pragma unroll
            for (int mi = 0; mi < 4; ++mi)
#pragma unroll
                for (int ni = 0; ni < 4; ++ni)
                    acc[mi][ni] = __builtin_amdgcn_mfma_f32_16x16x32_bf16(
                        a[mi], bb[ni], acc[mi][ni], 0, 0, 0);
            __builtin_amdgcn_s_setprio(0);
        };

        f32x4 pa0 = pA[0], pa1 = pA[1];
        issueB(0);
        f32x4 na0 = pA[8], na1 = pA[9];
        issueB(1);
        asm volatile("s_waitcnt vmcnt(6)" ::: "memory");
        writeA(0, pa0, pa1);
        asm volatile("s_waitcnt lgkmcnt(0)" ::: "memory");

#pragma unroll 1
        for (int s = 0; s < 32; ++s) {
            if (s < 31) {
                asm volatile("s_waitcnt vmcnt(2)" ::: "memory");
                writeA(s + 1, na0, na1);
            } else {
                asm volatile("s_waitcnt vmcnt(0)" ::: "memory");
            }
            if (s < 30) {
                na0 = pA[(size_t)(s + 2) * 8];
                na1 = pA[(size_t)(s + 2) * 8 + 1];
                issueB(s + 2);
            }
            __builtin_amdgcn_s_barrier();
            asm volatile("" ::: "memory");
            computeSlab(s);
            asm volatile("" ::: "memory");
            asm volatile("s_waitcnt lgkmcnt(0)" ::: "memory");
            __builtin_amdgcn_s_barrier();
        }

#pragma unroll
        for (int mi = 0; mi < 4; ++mi) {
#pragma unroll
            for (int r = 0; r < 4; ++r) {
                const int grow = tm * 128 + wm * 64 + mi * 16 + (lane >> 4) * 4 + r;
                float* cp = C + (size_t)grow * 1024 + tn * 256 + wn * 64 + (lane & 15);
#pragma unroll
                for (int ni = 0; ni < 4; ++ni) cp[ni * 16] = acc[mi][ni][r];
            }
        }
    }
}

extern "C" void kernel_launch(void* const* d_in, const int* in_sizes, int n_in,
                              void* d_out, int out_size, void* d_ws, size_t ws_size,
                              hipStream_t stream) {
    const float* in     = (const float*)d_in[0];
    const float* W      = (const float*)d_in[1];
    const float* ldown  = (const float*)d_in[2];
    const float* lup    = (const float*)d_in[3];
    const float* lroute = (const float*)d_in[4];
    const int*   taskid = (const int*)d_in[5];
    float* out = (float*)d_out;

    // workspace carve (~8.2 MB)
    __bf16*   Wb0      = (__bf16*)d_ws;                         // 2 MB
    __bf16*   Wb1      = Wb0 + (size_t)DOUT * DIN;              // 2 MB
    float*    partial2 = (float*)(Wb1 + (size_t)DOUT * DIN);    // 32 KB
    float*    gate     = partial2 + 8 * DIN;                    // 16 f
    int*      gidx     = (int*)(gate + 16);                     // 16 i
    unsigned* cnt      = (unsigned*)(gidx + 16);                // 16 u
    float*    partial  = (float*)(cnt + 16);                    // 4 MB

    hipMemsetAsync(cnt, 0, 16 * sizeof(unsigned), stream);
    kFused<<<512, 512, 0, stream>>>(in, W, ldown, lup, lroute, taskid,
                                    Wb0, Wb1, partial, partial2, gate, gidx,
                                    cnt, out);
}

// Round 14
// 127.567 us; speedup vs baseline: 2.0790x; 2.0790x over previous
//
#include <hip/hip_runtime.h>
#include <hip/hip_bf16.h>

typedef __attribute__((ext_vector_type(8))) __bf16 bf16x8;
typedef __attribute__((ext_vector_type(4))) __bf16 bf16x4;
typedef __attribute__((ext_vector_type(4))) float f32x4;

#define DIN 1024
#define DOUT 1024
#define MROWS 16384
#define POOLN 5
#define RR 8
#define NTASKS 5
#define TOPKK 3

// ---------------- kFront: colsum+omega -> flag barrier -> gate -> weights -----
// 512 blocks x 256 threads. Co-residency guaranteed: 512 = 2 blocks/CU x 256 CU,
// thread cap allows 8 blocks/CU, LDS ~1KB, VGPR capped by launch_bounds(256,4).
// Sync = flag ARRAY (one u32 per block, release-store + poll) — NO same-address
// atomic RMW (R13 lesson: 512 atomicAdds to one address ~= 51us serialized).
__global__ __launch_bounds__(256, 4) void kFront(
        const float* __restrict__ in, const float* __restrict__ W,
        const float* __restrict__ ldown, const float* __restrict__ lup,
        const float* __restrict__ lroute, const int* __restrict__ task_id_p,
        __bf16* __restrict__ Wb0, __bf16* __restrict__ Wb1,
        float* __restrict__ omgpart, unsigned* __restrict__ flags) {
    __shared__ float red[4][POOLN];
    __shared__ float sgate[TOPKK];
    __shared__ int   sgidx[TOPKK];
    const int b = blockIdx.x;       // 0..511
    const int t = threadIdx.x;      // 0..255
    const int w = t >> 6, l = t & 63;

    // ---- Phase A: sum this block's 32 rows (two 16-row streams, 4 loads in flight).
    // Thread t owns columns 4t..4t+3 (constant across rows).
    const f32x4* __restrict__ inv = (const f32x4*)in;
    float s0 = 0.f, s1 = 0.f, s2 = 0.f, s3 = 0.f;
    size_t ia = (size_t)b * 32 * 256 + t;
    size_t ib = ia + 16 * 256;
    f32x4 ca = inv[ia], cb = inv[ib];
#pragma unroll
    for (int i = 0; i < 16; ++i) {
        f32x4 na = ca, nb = cb;
        if (i < 15) { na = inv[ia + 256]; nb = inv[ib + 256]; }
        s0 += ca[0] + cb[0]; s1 += ca[1] + cb[1];
        s2 += ca[2] + cb[2]; s3 += ca[3] + cb[3];
        ca = na; cb = nb; ia += 256; ib += 256;
    }

    // ---- per-thread omega contribution: om[p] = sum_j s_j * route[1][4t+j][p]
    // route slice for d=4t..4t+3 is 20 contiguous floats.
    float om[POOLN];
    {
        const float* rp = &lroute[(size_t)DIN * POOLN + (size_t)(4 * t) * POOLN];
        const float sj[4] = { s0, s1, s2, s3 };
#pragma unroll
        for (int p = 0; p < POOLN; ++p) om[p] = 0.f;
#pragma unroll
        for (int j = 0; j < 4; ++j)
#pragma unroll
            for (int p = 0; p < POOLN; ++p)
                om[p] += sj[j] * rp[j * POOLN + p];
    }
#pragma unroll
    for (int p = 0; p < POOLN; ++p) {
        float v = om[p];
        for (int off = 32; off; off >>= 1) v += __shfl_down(v, off);
        if (l == 0) red[w][p] = v;
    }
    __syncthreads();
    if (t == 0) {
#pragma unroll
        for (int p = 0; p < POOLN; ++p)
            omgpart[b * 8 + p] = red[0][p] + red[1][p] + red[2][p] + red[3][p];
        __threadfence();    // release: omgpart visible before flag
        __hip_atomic_store(&flags[b], 1u, __ATOMIC_RELEASE, __HIP_MEMORY_SCOPE_AGENT);
    }

    // ---- flag barrier: thread t waits on flags[t] and flags[t+256]. No RMW.
    while (__hip_atomic_load(&flags[t], __ATOMIC_RELAXED, __HIP_MEMORY_SCOPE_AGENT) == 0u)
        __builtin_amdgcn_s_sleep(8);
    while (__hip_atomic_load(&flags[t + 256], __ATOMIC_RELAXED, __HIP_MEMORY_SCOPE_AGENT) == 0u)
        __builtin_amdgcn_s_sleep(8);
    __syncthreads();
    __threadfence();        // acquire: see all blocks' omgpart

    // ---- gate: every block redundantly reduces omgpart[512][8] (16KB, L3-served)
    {
        float acc[POOLN];
#pragma unroll
        for (int p = 0; p < POOLN; ++p)
            acc[p] = omgpart[t * 8 + p] + omgpart[(t + 256) * 8 + p];
#pragma unroll
        for (int p = 0; p < POOLN; ++p) {
            float v = acc[p];
            for (int off = 32; off; off >>= 1) v += __shfl_down(v, off);
            if (l == 0) red[w][p] = v;
        }
        __syncthreads();
        if (t == 0) {
            float part[POOLN];
#pragma unroll
            for (int p = 0; p < POOLN; ++p)
                part[p] = (red[0][p] + red[1][p] + red[2][p] + red[3][p]) * (1.0f / (float)MROWS);
            int tid = *task_id_p;
            if (tid > NTASKS) tid = NTASKS;
            int L = tid < (POOLN - 1) ? tid : (POOLN - 1);   // slice [1:tid+1] clamps
            int k = tid < TOPKK ? tid : TOPKK;
            float sl[POOLN];
            for (int j = 0; j < L; ++j) sl[j] = part[1 + j];
            float G[TOPKK]; int I[TOPKK];
            int used = 0;
            for (int j = 0; j < k; ++j) {
                int best = -1; float bv = 0.f;
                for (int i2 = 0; i2 < L; ++i2) {
                    if (used & (1 << i2)) continue;
                    if (best < 0 || sl[i2] > bv) { bv = sl[i2]; best = i2; }
                }
                used |= 1 << best; G[j] = bv; I[j] = best;
            }
            float gt[TOPKK] = {0.f, 0.f, 0.f};
            int   gi[TOPKK] = {0, 0, 0};
            if (k > 0) {
                float m = G[0];       // descending -> max first
                float e[TOPKK]; float se = 0.f;
                for (int j = 0; j < k; ++j) { e[j] = expf(G[j] - m); se += e[j]; }
                for (int j = 0; j < k; ++j) { gt[j] = e[j] / se; gi[j] = I[j]; }
            }
#pragma unroll
            for (int j = 0; j < TOPKK; ++j) { sgate[j] = gt[j]; sgidx[j] = gi[j]; }
        }
        __syncthreads();
    }

    // ---- weights: this block builds rows o = 2b and 2b+1
#pragma unroll
    for (int rep = 0; rep < 2; ++rep) {
        const int o = b * 2 + rep;
        float c[TOPKK][RR];
#pragma unroll
        for (int j = 0; j < TOPKK; ++j) {
            const float g = sgate[j];
            const int   p = sgidx[j];
#pragma unroll
            for (int r = 0; r < RR; ++r)
                c[j][r] = g * lup[(size_t)p * RR * DOUT + (size_t)r * DOUT + o];
        }
        const int d0 = t * 4;
        const float4 wv = *(const float4*)&W[(size_t)o * DIN + d0];
        float outv[4] = { wv.x, wv.y, wv.z, wv.w };
        float dwv[4]  = { 0.f, 0.f, 0.f, 0.f };
#pragma unroll
        for (int j = 0; j < TOPKK; ++j) {
            const int p = sgidx[j];
#pragma unroll
            for (int dd = 0; dd < 4; ++dd) {
                const float4 da = *(const float4*)&ldown[(size_t)p * DIN * RR + (size_t)(d0 + dd) * RR];
                const float4 db = *(const float4*)&ldown[(size_t)p * DIN * RR + (size_t)(d0 + dd) * RR + 4];
                dwv[dd] += da.x * c[j][0] + da.y * c[j][1] + da.z * c[j][2] + da.w * c[j][3]
                         + db.x * c[j][4] + db.y * c[j][5] + db.z * c[j][6] + db.w * c[j][7];
            }
        }
        bf16x4 b0 = { (__bf16)outv[0], (__bf16)outv[1], (__bf16)outv[2], (__bf16)outv[3] };
        bf16x4 b1 = { (__bf16)(outv[0] + dwv[0]), (__bf16)(outv[1] + dwv[1]),
                      (__bf16)(outv[2] + dwv[2]), (__bf16)(outv[3] + dwv[3]) };
        *(bf16x4*)&Wb0[(size_t)o * DIN + d0] = b0;
        *(bf16x4*)&Wb1[(size_t)o * DIN + d0] = b1;
    }
}

// ---------------- K4: 128x256 GEMM, f32-A converted in-kernel (R12 verbatim) --
__global__ __launch_bounds__(512, 4) void k4_gemm(const float* __restrict__ A,
                                                  const __bf16* __restrict__ B0,
                                                  const __bf16* __restrict__ B1,
                                                  float* __restrict__ C) {
    __shared__ ushort lds[36864];              // 72 KB; slab p at p*12288 ushorts
    const int bid = blockIdx.x;                // 0..511
    const int xcd = bid & 7;
    const int idx = bid >> 3;                  // 0..63
    const int tm  = xcd * 16 + (idx >> 2);     // 0..127 ; same-XCD blocks share A-panels
    const int tn  = idx & 3;                   // 0..3
    const __bf16* __restrict__ Bt = (tm >= 64) ? B1 : B0;   // rows >= 8192 get +delta

    const int tix  = threadIdx.x;
    const int lane = tix & 63;
    const int wid  = tix >> 6;                 // 0..7
    const int wm = wid >> 2, wn = wid & 3;     // 2M x 4N wave grid

    const int ar = tix >> 2;                   // 0..127
    const int ac = tix & 3;                    // 8-float chunk
    const f32x4* __restrict__ pA = (const f32x4*)(A + ((size_t)(tm * 128 + ar)) * 1024 + ac * 8);
    const int awrp  = tix >> 3;                        // rowpair 0..63
    const int awslot= ((tix & 3) + 4 * ((tix >> 2) & 1)) ^ (awrp & 7);
    const int awoff = awrp * 64 + awslot * 8;          // ushorts within A region

    const int rpl  = lane >> 3;                // local rowpair 0..7
    const int sl   = (lane & 7) ^ rpl;         // logical c + 4*parity
    const int srow = rpl * 2 + (sl >> 2);      // 0..15
    const int sc   = sl & 3;                   // 16B k-chunk
    const char* gB = (const char*)Bt + ((size_t)(tn*256 + wid*32 + srow)) * 2048 + sc * 16;
    const int ldsBst = 4096 + wid * 1024;      // ushort idx within slab (B region)

    const int rhalf = (lane & 15) >> 1;
    const int slot  = ((lane >> 4) + 4 * (lane & 1)) ^ rhalf;
    const int aoff  = (wm * 32 + rhalf) * 64 + slot * 8;          // + p*12288 + mi*512
    const int boff  = 4096 + (wn * 32 + rhalf) * 64 + slot * 8;   // + p*12288 + ni*512

    f32x4 acc[4][4];
#pragma unroll
    for (int i = 0; i < 4; ++i)
#pragma unroll
        for (int j = 0; j < 4; ++j) acc[i][j] = (f32x4){0.f, 0.f, 0.f, 0.f};

    auto issueB = [&](int s) {
        const int p = s % 3;
        const size_t kb = (size_t)s * 64;      // 32 bf16 = 64 B per k-slab
#pragma unroll
        for (int j = 0; j < 2; ++j) {
            __builtin_amdgcn_global_load_lds(
                (const __attribute__((address_space(1))) void*)(gB + (size_t)j * 32768 + kb),
                (__attribute__((address_space(3))) void*)&lds[p * 12288 + ldsBst + j * 512],
                16, 0, 0);
        }
    };

    auto writeA = [&](int s, f32x4 a0, f32x4 a1) {
        const int p = s % 3;
        bf16x8 v = { (__bf16)a0[0], (__bf16)a0[1], (__bf16)a0[2], (__bf16)a0[3],
                     (__bf16)a1[0], (__bf16)a1[1], (__bf16)a1[2], (__bf16)a1[3] };
        *(bf16x8*)&lds[p * 12288 + awoff] = v;
    };

    auto computeSlab = [&](int s) {
        const int p = s % 3;
        const ushort* aB = &lds[p * 12288 + aoff];
        const ushort* bB = &lds[p * 12288 + boff];
        bf16x8 a[4], b[4];
#pragma unroll
        for (int mi = 0; mi < 4; ++mi) a[mi] = *(const bf16x8*)(aB + mi * 512);
#pragma unroll
        for (int ni = 0; ni < 4; ++ni) b[ni] = *(const bf16x8*)(bB + ni * 512);
        __builtin_amdgcn_s_setprio(1);
#pragma unroll
        for (int mi = 0; mi < 4; ++mi)
#pragma unroll
            for (int ni = 0; ni < 4; ++ni)
                acc[mi][ni] = __builtin_amdgcn_mfma_f32_16x16x32_bf16(
                    a[mi], b[ni], acc[mi][ni], 0, 0, 0);
        __builtin_amdgcn_s_setprio(0);
    };

    f32x4 pa0 = pA[0], pa1 = pA[1];            // A(0)
    issueB(0);
    f32x4 na0 = pA[8], na1 = pA[9];            // A(1)
    issueB(1);
    asm volatile("s_waitcnt vmcnt(6)" ::: "memory");   // retire A(0) regs
    writeA(0, pa0, pa1);
    asm volatile("s_waitcnt lgkmcnt(0)" ::: "memory"); // A(0) visible pre-loop

#pragma unroll 1
    for (int s = 0; s < 32; ++s) {
        if (s < 31) {
            asm volatile("s_waitcnt vmcnt(2)" ::: "memory");  // retire B(s)+Areg(s+1)
            writeA(s + 1, na0, na1);
        } else {
            asm volatile("s_waitcnt vmcnt(0)" ::: "memory");
        }
        if (s < 30) {
            na0 = pA[(size_t)(s + 2) * 8];
            na1 = pA[(size_t)(s + 2) * 8 + 1];
            issueB(s + 2);
        }
        __builtin_amdgcn_s_barrier();                         // slab s fully staged
        asm volatile("" ::: "memory");
        computeSlab(s);
        asm volatile("" ::: "memory");
        asm volatile("s_waitcnt lgkmcnt(0)" ::: "memory");    // drain writeA(s+1), overlapped
        __builtin_amdgcn_s_barrier();
    }

#pragma unroll
    for (int mi = 0; mi < 4; ++mi) {
#pragma unroll
        for (int r = 0; r < 4; ++r) {
            const int grow = tm * 128 + wm * 64 + mi * 16 + (lane >> 4) * 4 + r;
            float* cp = C + (size_t)grow * 1024 + tn * 256 + wn * 64 + (lane & 15);
#pragma unroll
            for (int ni = 0; ni < 4; ++ni) cp[ni * 16] = acc[mi][ni][r];
        }
    }
}

extern "C" void kernel_launch(void* const* d_in, const int* in_sizes, int n_in,
                              void* d_out, int out_size, void* d_ws, size_t ws_size,
                              hipStream_t stream) {
    const float* in     = (const float*)d_in[0];
    const float* W      = (const float*)d_in[1];
    const float* ldown  = (const float*)d_in[2];
    const float* lup    = (const float*)d_in[3];
    const float* lroute = (const float*)d_in[4];
    const int*   taskid = (const int*)d_in[5];
    float* out = (float*)d_out;

    // workspace carve (~4.1 MB)
    __bf16*   Wb0     = (__bf16*)d_ws;                          // 2 MB
    __bf16*   Wb1     = Wb0 + (size_t)DOUT * DIN;               // 2 MB
    float*    omgpart = (float*)(Wb1 + (size_t)DOUT * DIN);     // 16 KB
    unsigned* flags   = (unsigned*)(omgpart + 512 * 8);         // 2 KB

    hipMemsetAsync(flags, 0, 512 * sizeof(unsigned), stream);
    kFront<<<512, 256, 0, stream>>>(in, W, ldown, lup, lroute, taskid,
                                    Wb0, Wb1, omgpart, flags);
    k4_gemm<<<512, 512, 0, stream>>>(in, Wb0, Wb1, out);
}